// Round 1
// baseline (842.816 us; speedup 1.0000x reference)
//
#include <hip/hip_runtime.h>

typedef _Float16 f16;
typedef _Float16 f16x4 __attribute__((ext_vector_type(4)));
typedef _Float16 f16x8 __attribute__((ext_vector_type(8)));
typedef float f32x4 __attribute__((ext_vector_type(4)));

#define DEVI __device__ __forceinline__

static constexpr int CAP = 64;   // slots per row; P(deg>64 | lambda=16) ~ 1e-19

DEVI void g2l16(const void* g, void* l) {
  __builtin_amdgcn_global_load_lds(
      (const __attribute__((address_space(1))) void*)g,
      (__attribute__((address_space(3))) void*)l, 16, 0, 0);
}

DEVI f16x8 cvt8(float4 a, float4 b) {
  f16x8 r;
  r[0] = (f16)a.x; r[1] = (f16)a.y; r[2] = (f16)a.z; r[3] = (f16)a.w;
  r[4] = (f16)b.x; r[5] = (f16)b.y; r[6] = (f16)b.z; r[7] = (f16)b.w;
  return r;
}

// ---------------- W transpose+cast into MFMA-fragment-linear order --------------
// For W[K][N] (row-major): group idx16 = (kc*(N/16) + n16)*64 + l holds 8 f16:
//   n = n16*16 + (l&15),  k = kc*32 + (l>>4)*8 + j   (j = 0..7)
// => a (kb, bn) B-tile is a CONTIGUOUS blob; g2l16 staging and ds_read_b128
//    fragment reads are both lane-linear (conflict-free).
__global__ __launch_bounds__(256)
void prep_w(const float* __restrict__ W1, const float* __restrict__ W2,
            const float* __restrict__ W3, f16* __restrict__ WT1,
            f16* __restrict__ WT2, f16* __restrict__ WT3) {
  int t = blockIdx.x * 256 + threadIdx.x;
  const float* W; f16* O; int N; int u;
  if (t < 16384) {                       // W1: K=512,N=256 -> 16*16*64 groups
    W = W1; O = WT1; N = 256; u = t;
  } else if (t < 16384 + 8192) {         // W2: K=256,N=256 -> 8*16*64
    W = W2; O = WT2; N = 256; u = t - 16384;
  } else if (t < 16384 + 8192 + 2048) {  // W3: K=256,N=64  -> 8*4*64
    W = W3; O = WT3; N = 64;  u = t - 24576;
  } else return;
  const int per = (N >> 4) * 64;
  const int kc = u / per;
  const int rem = u - kc * per;
  const int l = rem & 63;
  const int n = ((rem >> 6) << 4) + (l & 15);
  const int kb = kc * 32 + ((l >> 4) << 3);
  f16x8 o;
#pragma unroll
  for (int j = 0; j < 8; ++j) o[j] = (f16)W[(size_t)(kb + j) * N + n];
  *(f16x8*)(O + (size_t)u * 8) = o;
}

// ---------------- bucket build: slots[r][p] = (col, val) ----------------
__global__ __launch_bounds__(256)
void build_slots(const int* __restrict__ row, const int* __restrict__ col,
                 const float* __restrict__ vals, int* __restrict__ cnt,
                 int2* __restrict__ slots, int E) {
  int e = blockIdx.x * 256 + threadIdx.x;
  if (e >= E) return;
  int r = row[e];
  int p = atomicAdd(&cnt[r], 1);
  if (p < CAP) slots[(size_t)r * CAP + p] = make_int2(col[e], __float_as_int(vals[e]));
}

// ---------------- GEMM: C[M][N](f16) = A[M][K] @ WT^T + bias ----------------
// BM=128, BK=32, 4 waves (2x2). Double-buffered LDS, 2-phase schedule:
// stage(k+1) issued BEFORE compute(k); one barrier per iter (T3 minimum recipe).
// Both LDS tiles in fragment-linear order -> all DS ops lane-linear, 0 conflicts.
template <int BN, bool AF32>
__global__ __launch_bounds__(256)
void gemm_kern(const void* __restrict__ Ap, const f16* __restrict__ WT,
               const float* __restrict__ bias, f16* __restrict__ C,
               int M, int K, int N) {
  constexpr int BM = 128;
  constexpr int NT = BN / 32;        // n-frags per wave
  constexpr int BFRAGS = BN / 16;    // n-frags per block
  constexpr int BSHOTS = BN / 64;    // 256-thread g2l16 shots per B tile
  __shared__ f16 As[2][BM * 32];
  __shared__ f16 Bs[2][BN * 32];

  const int tid = threadIdx.x;
  const int wave = tid >> 6, lane = tid & 63;
  const int wm = wave >> 1, wn = wave & 1;
  const int quad = lane >> 4, l16 = lane & 15;
  const int bm = blockIdx.x, bn = blockIdx.y;
  const int r0 = bm * BM;
  const int kiters = K >> 5;
  const int nfrag16 = N >> 4;

  f32x4 acc[4][NT];
#pragma unroll
  for (int mt = 0; mt < 4; ++mt)
#pragma unroll
    for (int nt = 0; nt < NT; ++nt) {
      f32x4 z = {0.f, 0.f, 0.f, 0.f};
      acc[mt][nt] = z;
    }

  // ---- prologue: stage kb=0 into buffer 0 ----
  {
#pragma unroll
    for (int s = 0; s < BSHOTS; ++s) {
      int i16 = s * 256 + tid;
      const f16* gp = WT + (((size_t)bn * BFRAGS) * 64 + i16) * 8;
      g2l16(gp, &Bs[0][(s * 256 + wave * 64) * 8]);
    }
    if constexpr (AF32) {
      const float* Af = (const float*)Ap;
#pragma unroll
      for (int s = 0; s < 2; ++s) {
        int i16 = s * 256 + tid;
        int g = i16 >> 6, la = i16 & 63;
        int row = min(r0 + g * 16 + (la & 15), M - 1);
        const float4* gp = (const float4*)(Af + (size_t)row * K + ((la >> 4) << 3));
        float4 v0 = gp[0], v1 = gp[1];
        *(f16x8*)&As[0][i16 * 8] = cvt8(v0, v1);
      }
    } else {
      const f16* Ah = (const f16*)Ap;
#pragma unroll
      for (int s = 0; s < 2; ++s) {
        int i16 = s * 256 + tid;
        int g = i16 >> 6, la = i16 & 63;
        int row = min(r0 + g * 16 + (la & 15), M - 1);
        const f16* gp = Ah + (size_t)row * K + ((la >> 4) << 3);
        g2l16(gp, &As[0][(s * 256 + wave * 64) * 8]);
      }
    }
  }
  __syncthreads();

  int c = 0;
  for (int kb = 0; kb < kiters; ++kb) {
    const bool more = (kb + 1) < kiters;
    float4 ra00, ra01, ra10, ra11;

    // ---- issue stage(kb+1) into buf c^1 BEFORE compute(kb) ----
    if (more) {
      const int kn = kb + 1;
#pragma unroll
      for (int s = 0; s < BSHOTS; ++s) {
        int i16 = s * 256 + tid;
        const f16* gp = WT + (((size_t)kn * nfrag16 + (size_t)bn * BFRAGS) * 64 + i16) * 8;
        g2l16(gp, &Bs[c ^ 1][(s * 256 + wave * 64) * 8]);
      }
      if constexpr (AF32) {
        const float* Af = (const float*)Ap;
        {
          int i16 = tid;
          int g = i16 >> 6, la = i16 & 63;
          int row = min(r0 + g * 16 + (la & 15), M - 1);
          const float4* gp = (const float4*)(Af + (size_t)row * K + kn * 32 + ((la >> 4) << 3));
          ra00 = gp[0]; ra01 = gp[1];
        }
        {
          int i16 = 256 + tid;
          int g = i16 >> 6, la = i16 & 63;
          int row = min(r0 + g * 16 + (la & 15), M - 1);
          const float4* gp = (const float4*)(Af + (size_t)row * K + kn * 32 + ((la >> 4) << 3));
          ra10 = gp[0]; ra11 = gp[1];
        }
      } else {
        const f16* Ah = (const f16*)Ap;
#pragma unroll
        for (int s = 0; s < 2; ++s) {
          int i16 = s * 256 + tid;
          int g = i16 >> 6, la = i16 & 63;
          int row = min(r0 + g * 16 + (la & 15), M - 1);
          const f16* gp = Ah + (size_t)row * K + kn * 32 + ((la >> 4) << 3);
          g2l16(gp, &As[c ^ 1][(s * 256 + wave * 64) * 8]);
        }
      }
    }

    // ---- compute(kb): fragment reads are lane-linear (conflict-free) ----
    f16x8 af[4], bf[NT];
#pragma unroll
    for (int mt = 0; mt < 4; ++mt)
      af[mt] = *(const f16x8*)&As[c][((wm * 4 + mt) * 64 + lane) * 8];
#pragma unroll
    for (int nt = 0; nt < NT; ++nt)
      bf[nt] = *(const f16x8*)&Bs[c][((wn * NT + nt) * 64 + lane) * 8];
#pragma unroll
    for (int mt = 0; mt < 4; ++mt)
#pragma unroll
      for (int nt = 0; nt < NT; ++nt)
        acc[mt][nt] = __builtin_amdgcn_mfma_f32_16x16x32_f16(af[mt], bf[nt], acc[mt][nt], 0, 0, 0);

    // ---- late half of the A stage (T14 split): cvt + conflict-free ds_write ----
    if constexpr (AF32) {
      if (more) {
        *(f16x8*)&As[c ^ 1][tid * 8] = cvt8(ra00, ra01);
        *(f16x8*)&As[c ^ 1][(256 + tid) * 8] = cvt8(ra10, ra11);
      }
    }
    __syncthreads();   // drains vmcnt+lgkm: buf c^1 fully staged for next iter
    c ^= 1;
  }

  // ---- epilogue: + bias, store f16 ----
  float bv[NT];
#pragma unroll
  for (int nt = 0; nt < NT; ++nt)
    bv[nt] = bias[bn * BN + wn * (BN / 2) + nt * 16 + l16];
#pragma unroll
  for (int mt = 0; mt < 4; ++mt) {
#pragma unroll
    for (int nt = 0; nt < NT; ++nt) {
      int colg = bn * BN + wn * (BN / 2) + nt * 16 + l16;
#pragma unroll
      for (int r = 0; r < 4; ++r) {
        int grow = r0 + wm * 64 + mt * 16 + quad * 4 + r;
        if (grow < M)
          C[(size_t)grow * N + colg] = (f16)(acc[mt][nt][r] + bv[nt]);
      }
    }
  }
}

// ---------------- SpMM (F=256) + ReLU: H[i] = relu(sum vals*T[col]) ----------------
__global__ __launch_bounds__(256)
void spmm_relu256(const f16* __restrict__ T, const int2* __restrict__ slots,
                  const int* __restrict__ cnt, f16* __restrict__ H, int nrows) {
  const int wave = threadIdx.x >> 6, lane = threadIdx.x & 63;
  const int i = blockIdx.x * 4 + wave;
  if (i >= nrows) return;
  const int c = min(cnt[i], CAP);
  const int2* sl = slots + (size_t)i * CAP;
  float a0 = 0.f, a1 = 0.f, a2 = 0.f, a3 = 0.f;
  int j = 0;
  for (; j + 4 <= c; j += 4) {
    int2 e0 = sl[j], e1 = sl[j + 1], e2 = sl[j + 2], e3 = sl[j + 3];
    f16x4 u0 = ((const f16x4*)(T + (size_t)e0.x * 256))[lane];
    f16x4 u1 = ((const f16x4*)(T + (size_t)e1.x * 256))[lane];
    f16x4 u2 = ((const f16x4*)(T + (size_t)e2.x * 256))[lane];
    f16x4 u3 = ((const f16x4*)(T + (size_t)e3.x * 256))[lane];
    float v0 = __int_as_float(e0.y), v1 = __int_as_float(e1.y);
    float v2 = __int_as_float(e2.y), v3 = __int_as_float(e3.y);
    a0 += v0 * (float)u0.x + v1 * (float)u1.x + v2 * (float)u2.x + v3 * (float)u3.x;
    a1 += v0 * (float)u0.y + v1 * (float)u1.y + v2 * (float)u2.y + v3 * (float)u3.y;
    a2 += v0 * (float)u0.z + v1 * (float)u1.z + v2 * (float)u2.z + v3 * (float)u3.z;
    a3 += v0 * (float)u0.w + v1 * (float)u1.w + v2 * (float)u2.w + v3 * (float)u3.w;
  }
  for (; j < c; ++j) {
    int2 e = sl[j];
    f16x4 u = ((const f16x4*)(T + (size_t)e.x * 256))[lane];
    float v = __int_as_float(e.y);
    a0 += v * (float)u.x; a1 += v * (float)u.y;
    a2 += v * (float)u.z; a3 += v * (float)u.w;
  }
  f16x4 o;
  o.x = (f16)fmaxf(a0, 0.f); o.y = (f16)fmaxf(a1, 0.f);
  o.z = (f16)fmaxf(a2, 0.f); o.w = (f16)fmaxf(a3, 0.f);
  ((f16x4*)(H + (size_t)i * 256))[lane] = o;
}

// ---------------- SpMM (F=64), fp32 out, no activation ----------------
__global__ __launch_bounds__(256)
void spmm_out64(const f16* __restrict__ T, const int2* __restrict__ slots,
                const int* __restrict__ cnt, float* __restrict__ out, int nrows) {
  const int wave = threadIdx.x >> 6, lane = threadIdx.x & 63;
  const int i = blockIdx.x * 4 + wave;
  if (i >= nrows) return;
  const int c = min(cnt[i], CAP);
  const int2* sl = slots + (size_t)i * CAP;
  float a = 0.f;
  int j = 0;
  for (; j + 4 <= c; j += 4) {
    int2 e0 = sl[j], e1 = sl[j + 1], e2 = sl[j + 2], e3 = sl[j + 3];
    float u0 = (float)T[(size_t)e0.x * 64 + lane];
    float u1 = (float)T[(size_t)e1.x * 64 + lane];
    float u2 = (float)T[(size_t)e2.x * 64 + lane];
    float u3 = (float)T[(size_t)e3.x * 64 + lane];
    a += __int_as_float(e0.y) * u0 + __int_as_float(e1.y) * u1
       + __int_as_float(e2.y) * u2 + __int_as_float(e3.y) * u3;
  }
  for (; j < c; ++j) {
    int2 e = sl[j];
    a += __int_as_float(e.y) * (float)T[(size_t)e.x * 64 + lane];
  }
  out[(size_t)i * 64 + lane] = a;
}

extern "C" void kernel_launch(void* const* d_in, const int* in_sizes, int n_in,
                              void* d_out, int out_size, void* d_ws, size_t ws_size,
                              hipStream_t stream) {
  const float* x    = (const float*)d_in[0];
  const int*   row  = (const int*)d_in[1];
  const int*   col  = (const int*)d_in[2];
  const float* vals = (const float*)d_in[3];
  const float* W1   = (const float*)d_in[4];
  const float* b1   = (const float*)d_in[5];
  const float* W2   = (const float*)d_in[6];
  const float* b2   = (const float*)d_in[7];
  const float* W3   = (const float*)d_in[8];
  const float* b3   = (const float*)d_in[9];
  float* out = (float*)d_out;

  const int N = in_sizes[0] / 512;   // 100000
  const int E = in_sizes[1];         // 1600000

  // workspace layout (~153 MiB total)
  char* ws = (char*)d_ws;
  const size_t MiB = 1ull << 20;
  int*  cnt   = (int*)ws;                   // 0.4 MB
  int2* slots = (int2*)(ws + 1 * MiB);      // N*64*8 = 51.2 MB
  f16*  WT1   = (f16*)(ws + 52 * MiB);      // 0.26 MB
  f16*  WT2   = WT1 + 256 * 512;
  f16*  WT3   = WT2 + 256 * 256;
  f16*  T     = (f16*)(ws + 53 * MiB);      // N*256*2 = 51.2 MB
  f16*  H     = (f16*)(ws + 104 * MiB);     // N*256*2 = 51.2 MB

  hipMemsetAsync(cnt, 0, (size_t)N * sizeof(int), stream);
  prep_w<<<(16384 + 8192 + 2048 + 255) / 256, 256, 0, stream>>>(W1, W2, W3, WT1, WT2, WT3);
  build_slots<<<(E + 255) / 256, 256, 0, stream>>>(row, col, vals, cnt, slots, E);

  dim3 g12((N + 127) / 128, 2);
  dim3 g3((N + 127) / 128, 1);
  dim3 gs((N + 3) / 4);

  // layer 1
  gemm_kern<128, true><<<g12, 256, 0, stream>>>(x, WT1, b1, T, N, 512, 256);
  spmm_relu256<<<gs, 256, 0, stream>>>(T, slots, cnt, H, N);
  // layer 2
  gemm_kern<128, false><<<g12, 256, 0, stream>>>(H, WT2, b2, T, N, 256, 256);
  spmm_relu256<<<gs, 256, 0, stream>>>(T, slots, cnt, H, N);
  // layer 3
  gemm_kern<64, false><<<g3, 256, 0, stream>>>(H, WT3, b3, T, N, 256, 64);
  spmm_out64<<<gs, 256, 0, stream>>>(T, slots, cnt, out, N);
}

// Round 2
// 810.452 us; speedup vs baseline: 1.0399x; 1.0399x over previous
//
#include <hip/hip_runtime.h>

typedef _Float16 f16;
typedef _Float16 f16x4 __attribute__((ext_vector_type(4)));
typedef _Float16 f16x8 __attribute__((ext_vector_type(8)));
typedef float f32x4 __attribute__((ext_vector_type(4)));

#define DEVI __device__ __forceinline__

static constexpr int CAP = 64;   // slots per row; P(deg>64 | lambda=16) ~ 1e-19

DEVI f16x8 cvt8(float4 a, float4 b) {
  f16x8 r;
  r[0] = (f16)a.x; r[1] = (f16)a.y; r[2] = (f16)a.z; r[3] = (f16)a.w;
  r[4] = (f16)b.x; r[5] = (f16)b.y; r[6] = (f16)b.z; r[7] = (f16)b.w;
  return r;
}

// ---------------- W transpose+cast into MFMA-fragment-linear order --------------
// Group idx16 = (kc*(N/16) + n16)*64 + l holds 8 f16:
//   n = n16*16 + (l&15),  k = kc*32 + (l>>4)*8 + j   (j = 0..7)
// => B fragments are contiguous 16B/lane loads (coalesced, L2-friendly).
__global__ __launch_bounds__(256)
void prep_w(const float* __restrict__ W1, const float* __restrict__ W2,
            const float* __restrict__ W3, f16* __restrict__ WT1,
            f16* __restrict__ WT2, f16* __restrict__ WT3) {
  int t = blockIdx.x * 256 + threadIdx.x;
  const float* W; f16* O; int N; int u;
  if (t < 16384) {                       // W1: K=512,N=256 -> 16*16*64 groups
    W = W1; O = WT1; N = 256; u = t;
  } else if (t < 16384 + 8192) {         // W2: K=256,N=256 -> 8*16*64
    W = W2; O = WT2; N = 256; u = t - 16384;
  } else if (t < 16384 + 8192 + 2048) {  // W3: K=256,N=64  -> 8*4*64
    W = W3; O = WT3; N = 64;  u = t - 24576;
  } else return;
  const int per = (N >> 4) * 64;
  const int kc = u / per;
  const int rem = u - kc * per;
  const int l = rem & 63;
  const int n = ((rem >> 6) << 4) + (l & 15);
  const int kb = kc * 32 + ((l >> 4) << 3);
  f16x8 o;
#pragma unroll
  for (int j = 0; j < 8; ++j) o[j] = (f16)W[(size_t)(kb + j) * N + n];
  *(f16x8*)(O + (size_t)u * 8) = o;
}

// ---------------- bucket build: slots[r][p] = (col, val) ----------------
__global__ __launch_bounds__(256)
void build_slots(const int* __restrict__ row, const int* __restrict__ col,
                 const float* __restrict__ vals, int* __restrict__ cnt,
                 int2* __restrict__ slots, int E) {
  int e = blockIdx.x * 256 + threadIdx.x;
  if (e >= E) return;
  int r = row[e];
  int p = atomicAdd(&cnt[r], 1);
  if (p < CAP) slots[(size_t)r * CAP + p] = make_int2(col[e], __float_as_int(vals[e]));
}

// ---------------- Layer-1 GEMM: C[M][256](f16) = A[M][512](f32) @ W1 + b1 -------
// BM=64, 4 waves; wave w owns cols [w*64, w*64+64). K split in 2 chunks of 256.
// A is staged as ONE CONTIGUOUS 64KB sequential HBM stream per chunk (DRAM-
// friendly), cvt to f16 into a 32KB XOR-swizzled LDS tile. B fragments are read
// directly from global WT1 (512KB, L2-resident). Only 3 barriers per block.
__global__ __launch_bounds__(256)
void gemm_l1(const float* __restrict__ A, const f16* __restrict__ WT,
             const float* __restrict__ bias, f16* __restrict__ C, int M) {
  constexpr int K = 512, N = 256, NF16 = N / 16;
  __shared__ f16 As[64 * 256];   // [row][k within chunk], byte ^= ((row&7)<<4)

  const int tid = threadIdx.x;
  const int wave = tid >> 6, lane = tid & 63;
  const int quad = lane >> 4, l16 = lane & 15;
  const int r0 = blockIdx.x * 64;

  f32x4 acc[4][4];
#pragma unroll
  for (int mt = 0; mt < 4; ++mt)
#pragma unroll
    for (int nt = 0; nt < 4; ++nt) {
      f32x4 z = {0.f, 0.f, 0.f, 0.f};
      acc[mt][nt] = z;
    }

  for (int kc = 0; kc < 2; ++kc) {
    if (kc) __syncthreads();           // all waves done reading chunk 0
    // ---- stage: 64 rows x 256 k (fp32 -> f16). Linear streaming read:
    // 64 lanes of a wave cover 2 full rows (2KB each, contiguous). ----
#pragma unroll
    for (int it = 0; it < 8; ++it) {
      int i = it * 256 + tid;          // 16B-chunk index: 64 rows * 32 chunks
      int row = i >> 5, ko = i & 31;
      int grow = min(r0 + row, M - 1);
      const float4* gp = (const float4*)(A + (size_t)grow * K + kc * 256 + ko * 8);
      float4 v0 = gp[0], v1 = gp[1];
      int dst = (row * 512 + ko * 16) ^ ((row & 7) << 4);
      *(f16x8*)((char*)As + dst) = cvt8(v0, v1);
    }
    __syncthreads();
    // ---- compute: 8 k-iters, A from LDS (conflict-free), B from L2 ----
#pragma unroll
    for (int kb = 0; kb < 8; ++kb) {
      f16x8 af[4], bf[4];
#pragma unroll
      for (int mt = 0; mt < 4; ++mt) {
        int row = mt * 16 + l16;
        int src = (row * 512 + kb * 64 + quad * 16) ^ ((row & 7) << 4);
        af[mt] = *(const f16x8*)((char*)As + src);
      }
      const int kg = kc * 8 + kb;
#pragma unroll
      for (int nt = 0; nt < 4; ++nt) {
        int n16 = wave * 4 + nt;
        bf[nt] = *(const f16x8*)(WT + ((size_t)(kg * NF16 + n16) * 64 + lane) * 8);
      }
#pragma unroll
      for (int mt = 0; mt < 4; ++mt)
#pragma unroll
        for (int nt = 0; nt < 4; ++nt)
          acc[mt][nt] = __builtin_amdgcn_mfma_f32_16x16x32_f16(af[mt], bf[nt], acc[mt][nt], 0, 0, 0);
    }
  }

  // ---- epilogue: + bias, store f16 ----
  float bv[4];
#pragma unroll
  for (int nt = 0; nt < 4; ++nt) bv[nt] = bias[wave * 64 + nt * 16 + l16];
#pragma unroll
  for (int mt = 0; mt < 4; ++mt) {
#pragma unroll
    for (int nt = 0; nt < 4; ++nt) {
      int colg = wave * 64 + nt * 16 + l16;
#pragma unroll
      for (int r = 0; r < 4; ++r) {
        int grow = r0 + mt * 16 + quad * 4 + r;
        if (grow < M)
          C[(size_t)grow * N + colg] = (f16)(acc[mt][nt][r] + bv[nt]);
      }
    }
  }
}

// ---------------- Layers 2/3 GEMM: no-LDS, no-barrier, direct-fragment ----------
// A (f16, K=256) was just written -> L3-resident; fragment reads go to cache,
// not DRAM. Each wave = one independent 64x64 output tile (acc[4][4]).
// N = NTILES*64. Grid: ceil(M/64)*NTILES waves.
template <int NTILES>
__global__ __launch_bounds__(256)
void gemm_direct(const f16* __restrict__ A, const f16* __restrict__ WT,
                 const float* __restrict__ bias, f16* __restrict__ C, int M) {
  constexpr int K = 256, N = NTILES * 64, NF16 = N / 16;
  const int tid = threadIdx.x;
  const int wave = tid >> 6, lane = tid & 63;
  const int quad = lane >> 4, l16 = lane & 15;
  const int gw = blockIdx.x * 4 + wave;
  const int mtile = (NTILES == 1) ? gw : (gw / NTILES);
  const int ntile = (NTILES == 1) ? 0 : (gw % NTILES);
  const int r0 = mtile * 64;
  if (r0 >= M) return;

  size_t arow[4];
#pragma unroll
  for (int mt = 0; mt < 4; ++mt)
    arow[mt] = (size_t)min(r0 + mt * 16 + l16, M - 1) * K;

  f32x4 acc[4][4];
#pragma unroll
  for (int mt = 0; mt < 4; ++mt)
#pragma unroll
    for (int nt = 0; nt < 4; ++nt) {
      f32x4 z = {0.f, 0.f, 0.f, 0.f};
      acc[mt][nt] = z;
    }

#pragma unroll
  for (int kb = 0; kb < 8; ++kb) {
    f16x8 af[4], bf[4];
#pragma unroll
    for (int mt = 0; mt < 4; ++mt)
      af[mt] = *(const f16x8*)(A + arow[mt] + kb * 32 + quad * 8);
#pragma unroll
    for (int nt = 0; nt < 4; ++nt) {
      int n16 = ntile * 4 + nt;
      bf[nt] = *(const f16x8*)(WT + ((size_t)(kb * NF16 + n16) * 64 + lane) * 8);
    }
#pragma unroll
    for (int mt = 0; mt < 4; ++mt)
#pragma unroll
      for (int nt = 0; nt < 4; ++nt)
        acc[mt][nt] = __builtin_amdgcn_mfma_f32_16x16x32_f16(af[mt], bf[nt], acc[mt][nt], 0, 0, 0);
  }

  float bv[4];
#pragma unroll
  for (int nt = 0; nt < 4; ++nt) bv[nt] = bias[ntile * 64 + nt * 16 + l16];
#pragma unroll
  for (int mt = 0; mt < 4; ++mt) {
#pragma unroll
    for (int nt = 0; nt < 4; ++nt) {
      int colg = ntile * 64 + nt * 16 + l16;
#pragma unroll
      for (int r = 0; r < 4; ++r) {
        int grow = r0 + mt * 16 + quad * 4 + r;
        if (grow < M)
          C[(size_t)grow * N + colg] = (f16)(acc[mt][nt][r] + bv[nt]);
      }
    }
  }
}

// ---------------- SpMM (F=256) + ReLU: H[i] = relu(sum vals*T[col]) ----------------
__global__ __launch_bounds__(256)
void spmm_relu256(const f16* __restrict__ T, const int2* __restrict__ slots,
                  const int* __restrict__ cnt, f16* __restrict__ H, int nrows) {
  const int wave = threadIdx.x >> 6, lane = threadIdx.x & 63;
  const int i = blockIdx.x * 4 + wave;
  if (i >= nrows) return;
  const int c = min(cnt[i], CAP);
  const int2* sl = slots + (size_t)i * CAP;
  float a0 = 0.f, a1 = 0.f, a2 = 0.f, a3 = 0.f;
  int j = 0;
  for (; j + 4 <= c; j += 4) {
    int2 e0 = sl[j], e1 = sl[j + 1], e2 = sl[j + 2], e3 = sl[j + 3];
    f16x4 u0 = ((const f16x4*)(T + (size_t)e0.x * 256))[lane];
    f16x4 u1 = ((const f16x4*)(T + (size_t)e1.x * 256))[lane];
    f16x4 u2 = ((const f16x4*)(T + (size_t)e2.x * 256))[lane];
    f16x4 u3 = ((const f16x4*)(T + (size_t)e3.x * 256))[lane];
    float v0 = __int_as_float(e0.y), v1 = __int_as_float(e1.y);
    float v2 = __int_as_float(e2.y), v3 = __int_as_float(e3.y);
    a0 += v0 * (float)u0.x + v1 * (float)u1.x + v2 * (float)u2.x + v3 * (float)u3.x;
    a1 += v0 * (float)u0.y + v1 * (float)u1.y + v2 * (float)u2.y + v3 * (float)u3.y;
    a2 += v0 * (float)u0.z + v1 * (float)u1.z + v2 * (float)u2.z + v3 * (float)u3.z;
    a3 += v0 * (float)u0.w + v1 * (float)u1.w + v2 * (float)u2.w + v3 * (float)u3.w;
  }
  for (; j < c; ++j) {
    int2 e = sl[j];
    f16x4 u = ((const f16x4*)(T + (size_t)e.x * 256))[lane];
    float v = __int_as_float(e.y);
    a0 += v * (float)u.x; a1 += v * (float)u.y;
    a2 += v * (float)u.z; a3 += v * (float)u.w;
  }
  f16x4 o;
  o.x = (f16)fmaxf(a0, 0.f); o.y = (f16)fmaxf(a1, 0.f);
  o.z = (f16)fmaxf(a2, 0.f); o.w = (f16)fmaxf(a3, 0.f);
  ((f16x4*)(H + (size_t)i * 256))[lane] = o;
}

// ---------------- SpMM (F=64), fp32 out, no activation ----------------
__global__ __launch_bounds__(256)
void spmm_out64(const f16* __restrict__ T, const int2* __restrict__ slots,
                const int* __restrict__ cnt, float* __restrict__ out, int nrows) {
  const int wave = threadIdx.x >> 6, lane = threadIdx.x & 63;
  const int i = blockIdx.x * 4 + wave;
  if (i >= nrows) return;
  const int c = min(cnt[i], CAP);
  const int2* sl = slots + (size_t)i * CAP;
  float a = 0.f;
  int j = 0;
  for (; j + 4 <= c; j += 4) {
    int2 e0 = sl[j], e1 = sl[j + 1], e2 = sl[j + 2], e3 = sl[j + 3];
    float u0 = (float)T[(size_t)e0.x * 64 + lane];
    float u1 = (float)T[(size_t)e1.x * 64 + lane];
    float u2 = (float)T[(size_t)e2.x * 64 + lane];
    float u3 = (float)T[(size_t)e3.x * 64 + lane];
    a += __int_as_float(e0.y) * u0 + __int_as_float(e1.y) * u1
       + __int_as_float(e2.y) * u2 + __int_as_float(e3.y) * u3;
  }
  for (; j < c; ++j) {
    int2 e = sl[j];
    a += __int_as_float(e.y) * (float)T[(size_t)e.x * 64 + lane];
  }
  out[(size_t)i * 64 + lane] = a;
}

extern "C" void kernel_launch(void* const* d_in, const int* in_sizes, int n_in,
                              void* d_out, int out_size, void* d_ws, size_t ws_size,
                              hipStream_t stream) {
  const float* x    = (const float*)d_in[0];
  const int*   row  = (const int*)d_in[1];
  const int*   col  = (const int*)d_in[2];
  const float* vals = (const float*)d_in[3];
  const float* W1   = (const float*)d_in[4];
  const float* b1   = (const float*)d_in[5];
  const float* W2   = (const float*)d_in[6];
  const float* b2   = (const float*)d_in[7];
  const float* W3   = (const float*)d_in[8];
  const float* b3   = (const float*)d_in[9];
  float* out = (float*)d_out;

  const int N = in_sizes[0] / 512;   // 100000 nodes
  const int E = in_sizes[1];         // 1600000 edges

  // workspace layout (~153 MiB total)
  char* ws = (char*)d_ws;
  const size_t MiB = 1ull << 20;
  int*  cnt   = (int*)ws;                   // 0.4 MB
  int2* slots = (int2*)(ws + 1 * MiB);      // N*64*8 = 51.2 MB
  f16*  WT1   = (f16*)(ws + 52 * MiB);      // 0.26 MB
  f16*  WT2   = WT1 + 256 * 512;
  f16*  WT3   = WT2 + 256 * 256;
  f16*  T     = (f16*)(ws + 53 * MiB);      // N*256*2 = 51.2 MB
  f16*  H     = (f16*)(ws + 104 * MiB);     // N*256*2 = 51.2 MB

  hipMemsetAsync(cnt, 0, (size_t)N * sizeof(int), stream);
  prep_w<<<(16384 + 8192 + 2048 + 255) / 256, 256, 0, stream>>>(W1, W2, W3, WT1, WT2, WT3);
  build_slots<<<(E + 255) / 256, 256, 0, stream>>>(row, col, vals, cnt, slots, E);

  const int mt64 = (N + 63) / 64;    // 64-row tiles
  dim3 gs((N + 3) / 4);

  // layer 1: streaming-LDS GEMM (A fp32 from HBM, contiguous stream)
  gemm_l1<<<mt64, 256, 0, stream>>>(x, WT1, b1, T, N);
  spmm_relu256<<<gs, 256, 0, stream>>>(T, slots, cnt, H, N);
  // layer 2: direct-fragment GEMM (A f16, L3-resident)
  gemm_direct<4><<<mt64, 256, 0, stream>>>(H, WT2, b2, T, N);
  spmm_relu256<<<gs, 256, 0, stream>>>(T, slots, cnt, H, N);
  // layer 3: direct-fragment GEMM, N=64
  gemm_direct<1><<<(mt64 + 3) / 4, 256, 0, stream>>>(H, WT3, b3, T, N);
  spmm_out64<<<gs, 256, 0, stream>>>(T, slots, cnt, out, N);
}